// Round 1
// baseline (706.082 us; speedup 1.0000x reference)
//
#include <hip/hip_runtime.h>
#include <math.h>

#define H      2048
#define HV     512          // H/4
#define E      64
#define MTOK   8            // tokens per wave
#define T_TOK  32768        // 4*8192
#define GATES_OFF   0
#define IDX_OFF     65536
#define LOSS_OFF    131072

// ---------------- W transpose: W[e][h] -> Wt[(h/4)][e][h%4] (float4 per (h4,e)) ---
__global__ void transpose_w_kernel(const float* __restrict__ W, float* __restrict__ Wt) {
    int id = blockIdx.x * 256 + threadIdx.x;       // 131072 total
    int e = id >> 11;                               // / 2048
    int h = id & 2047;
    Wt[(h >> 2) * 256 + (e << 2) + (h & 3)] = W[id];
}

// ---------------- main gating kernel ----------------
__global__ __launch_bounds__(256) void gate_main_kernel(
        const float* __restrict__ x,         // (T, H)
        const float4* __restrict__ wt,       // [HV][E] float4
        float* __restrict__ out,
        float* __restrict__ accum)           // [0:64) sum probs, [64:128) counts
{
    const int lane = threadIdx.x & 63;
    const int wave = threadIdx.x >> 6;
    const int gwave = blockIdx.x * 4 + wave;
    const int tokBase = __builtin_amdgcn_readfirstlane(gwave * MTOK);

    const float4* __restrict__ xq = (const float4*)x + (size_t)tokBase * HV;

    float acc[MTOK];
#pragma unroll
    for (int m = 0; m < MTOK; ++m) acc[m] = 0.f;

    for (int i = 0; i < HV; ++i) {
        float4 wv = wt[i * E + lane];        // coalesced 16B/lane
#pragma unroll
        for (int m = 0; m < MTOK; ++m) {
            float4 xv = xq[m * HV + i];      // wave-uniform -> scalar load
            acc[m] = fmaf(xv.x, wv.x, acc[m]);
            acc[m] = fmaf(xv.y, wv.y, acc[m]);
            acc[m] = fmaf(xv.z, wv.z, acc[m]);
            acc[m] = fmaf(xv.w, wv.w, acc[m]);
        }
    }

    float sumP = 0.f, cntP = 0.f;

#pragma unroll
    for (int m = 0; m < MTOK; ++m) {
        float v = acc[m];                    // logit(token, expert=lane)

        // full softmax over 64 experts (for aux loss)
        float vmax = v;
#pragma unroll
        for (int d = 32; d > 0; d >>= 1) vmax = fmaxf(vmax, __shfl_xor(vmax, d, 64));
        float ex = expf(v - vmax);
        float s = ex;
#pragma unroll
        for (int d = 32; d > 0; d >>= 1) s += __shfl_xor(s, d, 64);
        float p = ex / s;
        sumP += p;
        cntP += (p > 0.f) ? 1.f : 0.f;

        // top-1 (tie -> lower index, matching lax.top_k)
        float v1 = v; int i1 = lane;
#pragma unroll
        for (int d = 32; d > 0; d >>= 1) {
            float ov = __shfl_xor(v1, d, 64);
            int   oi = __shfl_xor(i1, d, 64);
            if (ov > v1 || (ov == v1 && oi < i1)) { v1 = ov; i1 = oi; }
        }
        // top-2: mask out i1
        float v2 = (lane == i1) ? -INFINITY : v; int i2 = lane;
#pragma unroll
        for (int d = 32; d > 0; d >>= 1) {
            float ov = __shfl_xor(v2, d, 64);
            int   oi = __shfl_xor(i2, d, 64);
            if (ov > v2 || (ov == v2 && oi < i2)) { v2 = ov; i2 = oi; }
        }

        if (lane == 0) {
            int token = tokBase + m;
            float t  = expf(v2 - v1);        // softmax([v1,v2]) with max subtracted
            float d  = 1.f / (1.f + t);
            out[GATES_OFF + 2 * token]     = d;
            out[GATES_OFF + 2 * token + 1] = t * d;
            out[IDX_OFF   + 2 * token]     = (float)i1;
            out[IDX_OFF   + 2 * token + 1] = (float)i2;
        }
    }

    // block-level reduction of per-expert prob sums / counts, one atomic instr per block
    __shared__ float redP[4][64];
    __shared__ float redC[4][64];
    redP[wave][lane] = sumP;
    redC[wave][lane] = cntP;
    __syncthreads();
    if (wave == 0) {
        float sp = redP[0][lane] + redP[1][lane] + redP[2][lane] + redP[3][lane];
        float sc = redC[0][lane] + redC[1][lane] + redC[2][lane] + redC[3][lane];
        atomicAdd(&accum[lane], sp);
        atomicAdd(&accum[E + lane], sc);
    }
}

// ---------------- final loss kernel ----------------
__global__ void gate_final_kernel(const float* __restrict__ accum, float* __restrict__ out) {
    int lane = threadIdx.x;                  // 64 threads
    const float invT = 1.f / (float)T_TOK;
    float mean_p   = accum[lane] * invT;
    float routing  = accum[E + lane] * invT;
    float term = mean_p * routing;
#pragma unroll
    for (int d = 32; d > 0; d >>= 1) term += __shfl_xor(term, d, 64);
    if (lane == 0) out[LOSS_OFF] = 64.f * term;
}

extern "C" void kernel_launch(void* const* d_in, const int* in_sizes, int n_in,
                              void* d_out, int out_size, void* d_ws, size_t ws_size,
                              hipStream_t stream) {
    const float* x = (const float*)d_in[0];   // (4,8192,2048) fp32
    const float* W = (const float*)d_in[1];   // (64,2048) fp32
    float* out   = (float*)d_out;
    float* accum = (float*)d_ws;              // 128 floats
    float* Wt    = (float*)d_ws + 128;        // 131072 floats (16B-aligned)

    hipMemsetAsync(accum, 0, 128 * sizeof(float), stream);
    transpose_w_kernel<<<512, 256, 0, stream>>>(W, Wt);
    gate_main_kernel<<<T_TOK / (MTOK * 4), 256, 0, stream>>>(x, (const float4*)Wt, out, accum);
    gate_final_kernel<<<1, 64, 0, stream>>>(accum, out);
}